// Round 2
// baseline (625.786 us; speedup 1.0000x reference)
//
#include <hip/hip_runtime.h>
#include <math.h>

#define NB 4
#define NC 20
#define NH 480
#define NW 640
#define NPIX (NH*NW)      // 307200
#define NM 480
#define NVR 100
#define NNZ 80
#define ZLO 13
#define ZHI 25
#define NZB 12
#define NSEM_ 16
#define NBINS 101         // y0 bucket 0..100 (100 = dead)
#define SREC_CAP 655360   // band-record capacity (expected ~310K)
#define SLAB_GRID 300     // persistent blocks for fused slab kernel (1200 tiles / 300 = 4 each)

// workspace offsets
#define WS_HIST     0
#define WS_HIST2    2048
#define WS_STARTS   4096
#define WS_STARTS2  6144
#define WS_CURS     8192
#define WS_CURS2    10240
#define WS_PARAMS   12288
#define WS_RECS     16384
#define WS_PROJ     (WS_RECS + 19660800)           // 19,677,184
#define WS_SGEOM    (WS_PROJ + 3200000)            // 22,877,184
#define WS_FAST_END (WS_SGEOM + (size_t)SREC_CAP*16) // 33,362,944

// exact replication of the reference f32 op chains
__device__ __forceinline__ float p1_chain(float d) {
  float xy1 = d / 5.0f;
  xy1 = (xy1 - 50.0f) / 100.0f * 2.0f;
  return xy1 * 50.0f + 50.0f;
}
__device__ __forceinline__ void p02_chain(float d, int row, int col, float foc,
                                          float& p0, float& p2) {
  float X = ((float)col - 319.5f) * d / foc;
  float Z = ((float)(479 - row) - 239.5f) * d / foc;
  float xy0 = (X + 250.0f) / 5.0f;
  xy0 = (xy0 - 50.0f) / 100.0f * 2.0f;
  float zz = (Z + 88.0f) / 5.0f;
  zz = (zz - 32.0f) / 80.0f * 2.0f;
  p0 = xy0 * 50.0f + 50.0f;
  p2 = zz * 40.0f + 40.0f;
}
// true iff this record can produce any nonzero sem-band contribution
__device__ __forceinline__ bool band_ok(float p0, float p2) {
  return (p0 > 0.0f) && (p0 < 100.0f) &&
         (p2 > (float)(ZLO - 1)) && (p2 < (float)ZHI);
}

// ---------------- pose + affine params ----------------
__global__ __launch_bounds__(64) void pose_kernel(
    const float* __restrict__ pose_obs, const float* __restrict__ poses_last,
    float* __restrict__ out_poses, float* __restrict__ params)
{
  int b = threadIdx.x;
  if (b >= NB) return;
  const float R2D = 57.29577951308232f;
  float plx = poses_last[b*3+0], ply = poses_last[b*3+1], plo = poses_last[b*3+2];
  float dx = pose_obs[b*3+0], dy = pose_obs[b*3+1], dth = pose_obs[b*3+2];
  float r = plo / R2D;
  float sr = sinf(r), cr = cosf(r);
  float yy = ply + dx*sr + dy*cr;
  float xx = plx + dx*cr - dy*sr;
  float oo = plo + dth*R2D;
  oo = fmodf(oo - 180.0f, 360.0f) + 180.0f;
  oo = fmodf(oo + 180.0f, 360.0f) - 180.0f;
  out_poses[b*3+0] = xx;
  out_poses[b*3+1] = yy;
  out_poses[b*3+2] = oo;
  float tx = -((xx*100.0f/5.0f) - 240.0f) / 240.0f;
  float ty = -((yy*100.0f/5.0f) - 240.0f) / 240.0f;
  float th = ((90.0f - oo) * 3.14159274101257324f) / 180.0f;
  params[b*4+0] = cosf(th);
  params[b*4+1] = sinf(th);
  params[b*4+2] = tx;
  params[b*4+3] = ty;
}

// ---------------- histogram by y-bucket (all + band-filtered) ----------------
__global__ __launch_bounds__(256) void hist_kernel(
    const float* __restrict__ obs, int* __restrict__ hist, int* __restrict__ hist2,
    float foc)
{
  int b = blockIdx.x / 300, blk = blockIdx.x % 300;
  __shared__ int lh[NBINS], lh2[NBINS];
  for (int i = threadIdx.x; i < NBINS; i += 256) { lh[i] = 0; lh2[i] = 0; }
  __syncthreads();
  int pix0 = (blk*256 + threadIdx.x)*4;
  int row = pix0 / NW;
  int c0 = pix0 - row*NW;
  const float4* dp = (const float4*)(obs + ((size_t)b*NC + 3)*NPIX);
  float4 dv = dp[blk*256 + threadIdx.x];
  float dvv[4] = {dv.x, dv.y, dv.z, dv.w};
  #pragma unroll
  for (int k = 0; k < 4; ++k) {
    float p1 = p1_chain(dvv[k]);
    int y0 = (int)floorf(p1);
    y0 = min(max(y0, 0), 100);
    atomicAdd(&lh[y0], 1);
    float p0, p2;
    p02_chain(dvv[k], row, c0 + k, foc, p0, p2);
    if (band_ok(p0, p2)) atomicAdd(&lh2[y0], 1);
  }
  __syncthreads();
  for (int i = threadIdx.x; i < NBINS; i += 256) {
    if (lh[i])  atomicAdd(&hist[b*NBINS + i],  lh[i]);
    if (lh2[i]) atomicAdd(&hist2[b*NBINS + i], lh2[i]);
  }
}

// ---------------- exclusive scan of both bin arrays ----------------
__global__ __launch_bounds__(512) void scan_kernel(
    const int* __restrict__ hist, const int* __restrict__ hist2,
    int* __restrict__ starts, int* __restrict__ cursors,
    int* __restrict__ starts2, int* __restrict__ cursors2)
{
  __shared__ int lh[NB*NBINS], lh2[NB*NBINS];
  __shared__ int ls[NB*NBINS + 1], ls2[NB*NBINS + 1];
  for (int i = threadIdx.x; i < NB*NBINS; i += 512) { lh[i] = hist[i]; lh2[i] = hist2[i]; }
  __syncthreads();
  if (threadIdx.x == 0) {
    int s = 0;
    for (int i = 0; i < NB*NBINS; ++i) { ls[i] = s; s += lh[i]; }
    ls[NB*NBINS] = s;
  }
  if (threadIdx.x == 1) {
    int s = 0;
    for (int i = 0; i < NB*NBINS; ++i) { ls2[i] = s; s += lh2[i]; }
    ls2[NB*NBINS] = s;
  }
  __syncthreads();
  for (int i = threadIdx.x; i < NB*NBINS + 1; i += 512) {
    starts[i] = ls[i];
    starts2[i] = ls2[i];
    if (i < NB*NBINS) { cursors[i] = ls[i]; cursors2[i] = ls2[i]; }
  }
}

// ---------------- scatter pixel records into buckets ----------------
// Band records additionally go to the sgeom stream (geom + pixel id for sem gather).
__global__ __launch_bounds__(256) void scatter_kernel(
    const float* __restrict__ obs, int* __restrict__ cursors, int* __restrict__ cursors2,
    float4* __restrict__ recs, float4* __restrict__ sgeom,
    float foc, int do_band)
{
  int b = blockIdx.x / 300, blk = blockIdx.x % 300;
  __shared__ int lh[NBINS], lbase[NBINS], loff[NBINS];
  __shared__ int lh2[NBINS], lbase2[NBINS], loff2[NBINS];
  for (int i = threadIdx.x; i < NBINS; i += 256) {
    lh[i] = 0; loff[i] = 0; lh2[i] = 0; loff2[i] = 0;
  }
  __syncthreads();
  int pix0 = (blk*256 + threadIdx.x)*4;
  int row = pix0 / NW;
  int c0 = pix0 - row*NW;   // 4-pixel group never crosses a row (640 % 4 == 0)
  const float4* dp = (const float4*)(obs + ((size_t)b*NC + 3)*NPIX);
  float4 dv = dp[blk*256 + threadIdx.x];
  float dvv[4] = {dv.x, dv.y, dv.z, dv.w};
  float rp0[4], rp1[4], rp2[4]; int rbin[4]; bool rb[4];
  #pragma unroll
  for (int k = 0; k < 4; ++k) {
    float p1 = p1_chain(dvv[k]);
    float p0, p2;
    p02_chain(dvv[k], row, c0 + k, foc, p0, p2);
    rp0[k] = p0; rp1[k] = p1; rp2[k] = p2;
    int y0 = (int)floorf(p1); y0 = min(max(y0, 0), 100);
    rbin[k] = y0;
    atomicAdd(&lh[y0], 1);
    rb[k] = do_band && band_ok(p0, p2);
    if (rb[k]) atomicAdd(&lh2[y0], 1);
  }
  __syncthreads();
  for (int i = threadIdx.x; i < NBINS; i += 256) {
    if (lh[i]  > 0) lbase[i]  = atomicAdd(&cursors[b*NBINS + i],  lh[i]);
    if (lh2[i] > 0) lbase2[i] = atomicAdd(&cursors2[b*NBINS + i], lh2[i]);
  }
  __syncthreads();
  #pragma unroll
  for (int k = 0; k < 4; ++k) {
    int idx = atomicAdd(&loff[rbin[k]], 1);
    recs[lbase[rbin[k]] + idx] =
        make_float4(rp0[k], rp1[k], rp2[k], __int_as_float(pix0 + k));
    if (rb[k]) {
      int j = lbase2[rbin[k]] + atomicAdd(&loff2[rbin[k]], 1);
      if (j < SREC_CAP)
        sgeom[j] = make_float4(rp0[k], rp1[k], rp2[k], __int_as_float(pix0 + k));
    }
  }
}

// ---------------- fused persistent slab kernel ----------------
// 1200 tiles: t in [0,400) -> ch0 slab for (b=t/100, Y=t%100)
//             t in [400,1200) -> sem slab (tt=t-400; half=tt&1; b=(tt>>1)/100; Y=(tt>>1)%100)
// 300 persistent blocks, 4 tiles each; LDS re-zeroed per tile.
__global__ __launch_bounds__(256, 4) void slabs_kernel(
    const float* __restrict__ obs,
    const float4* __restrict__ recs, const float4* __restrict__ sgeom,
    const int* __restrict__ starts, const int* __restrict__ starts2,
    float* __restrict__ proj, float* __restrict__ out_fp)
{
  __shared__ float g[9600];   // 38400 B; slab0 uses [x:100][z:81]; slab1 uses [s:8][cell:1200]
  for (int t = blockIdx.x; t < 1200; t += SLAB_GRID) {
    __syncthreads();                         // previous tile's readers done before re-init
    for (int i = threadIdx.x; i < 9600; i += 256) g[i] = 0.0f;
    __syncthreads();
    if (t < 400) {
      // ---------- ch0 slab ----------
      int b = t / NVR, Y = t % NVR;
      if (Y > 0) {
        int lo = starts[b*NBINS + Y - 1];
        int hi = starts[b*NBINS + Y + 1];
        float Yf = (float)Y;
        for (int i = lo + threadIdx.x; i < hi; i += 256) {
          float4 r = recs[i];
          float wy = 1.0f - fabsf(r.y - Yf);
          if (wy <= 0.0f) continue;
          float p0 = r.x, p2 = r.z;
          float fl0 = floorf(p0), fl2 = floorf(p2);
          #pragma unroll
          for (int xo = 0; xo < 2; ++xo) {
            float px = fl0 + (float)xo;
            if (!(px > 0.0f && px < 100.0f)) continue;
            float wxy = (1.0f - fabsf(p0 - px)) * wy;
            if (wxy <= 0.0f) continue;
            int ix = (int)px;
            #pragma unroll
            for (int zo = 0; zo < 2; ++zo) {
              float pz = fl2 + (float)zo;
              if (!(pz > 0.0f && pz < 80.0f)) continue;
              float w = wxy * (1.0f - fabsf(p2 - pz));
              if (w > 0.0f) atomicAdd(&g[ix*81 + (int)pz], w);
            }
          }
        }
      }
      __syncthreads();
      if (threadIdx.x < NVR) {
        int x = threadIdx.x;
        float s_all = 0.0f, s_ag = 0.0f;
        for (int z = 0; z < NNZ; ++z) {
          float v = rintf(g[x*81 + z]);
          s_all += v;
          if (z >= ZLO && z < ZHI) s_ag += v;
        }
        float fp_map = fminf(fmaxf(s_ag, 0.0f), 1.0f);
        float fp_exp = fminf(fmaxf(s_all, 0.0f), 1.0f);
        size_t pb = (((size_t)b*NC + 0)*NVR + Y)*NVR + x;
        proj[pb] = fp_map;
        proj[pb + NVR*NVR] = fp_exp;
        proj[pb + 2*NVR*NVR] = 0.0f;
        proj[pb + 3*NVR*NVR] = 0.0f;
        out_fp[(size_t)b*NVR*NVR + Y*NVR + x] = fp_map;
      }
    } else {
      // ---------- sem slab (8 channels) ----------
      int tt = t - 400;
      int half = tt & 1;
      int by = tt >> 1;
      int b = by / NVR, Y = by % NVR;
      const float* sbase = obs + ((size_t)b*NC + 4 + half*8)*NPIX;
      if (Y > 0) {
        int lo = starts2[b*NBINS + Y - 1];
        int hi = starts2[b*NBINS + Y + 1];
        float Yf = (float)Y;
        for (int i = lo + threadIdx.x; i < hi; i += 256) {
          float4 r = sgeom[i];
          float wy = 1.0f - fabsf(r.y - Yf);
          if (wy <= 0.0f) continue;
          float p2 = r.z;
          float fl2 = floorf(p2);
          float wz[2]; int iz[2]; bool any = false;
          #pragma unroll
          for (int zo = 0; zo < 2; ++zo) {
            float pz = fl2 + (float)zo;
            bool v = (pz >= (float)ZLO) && (pz < (float)ZHI);
            float w = v ? (1.0f - fabsf(p2 - pz)) : 0.0f;
            wz[zo] = w; iz[zo] = v ? ((int)pz - ZLO) : 0;
            any = any || (w > 0.0f);
          }
          if (!any) continue;
          float p0 = r.x;
          float fl0 = floorf(p0);
          int pid = __float_as_int(r.w);
          float sem[8];
          #pragma unroll
          for (int s = 0; s < 8; ++s) sem[s] = sbase[(size_t)s*NPIX + pid];
          #pragma unroll
          for (int xo = 0; xo < 2; ++xo) {
            float px = fl0 + (float)xo;
            if (!(px > 0.0f && px < 100.0f)) continue;
            float wxy = (1.0f - fabsf(p0 - px)) * wy;
            if (wxy <= 0.0f) continue;
            int ix = (int)px;
            #pragma unroll
            for (int zo = 0; zo < 2; ++zo) {
              float w = wxy * wz[zo];
              if (w > 0.0f) {
                int cell = ix*NZB + iz[zo];
                #pragma unroll
                for (int s = 0; s < 8; ++s)
                  atomicAdd(&g[s*1200 + cell], w * sem[s]);
              }
            }
          }
        }
      }
      __syncthreads();
      for (int p = threadIdx.x; p < NVR*8; p += 256) {
        int x = p >> 3, s = p & 7;
        float acc = 0.0f;
        #pragma unroll
        for (int z = 0; z < NZB; ++z) acc += rintf(g[s*1200 + x*NZB + z]);
        float val = fminf(fmaxf(acc / 5.0f, 0.0f), 1.0f);
        proj[(((size_t)b*NC + 4 + half*8 + s)*NVR + Y)*NVR + x] = val;
      }
    }
  }
}

// ---------------- fallback (non-persistent) slab kernels ----------------
__global__ __launch_bounds__(256) void slab0_kernel(
    const float4* __restrict__ recs, const int* __restrict__ starts,
    float* __restrict__ proj, float* __restrict__ out_fp)
{
  int b = blockIdx.x / NVR, Y = blockIdx.x % NVR;
  __shared__ float g[NVR*81];
  for (int i = threadIdx.x; i < NVR*81; i += 256) g[i] = 0.0f;
  __syncthreads();
  if (Y > 0) {
    int lo = starts[b*NBINS + Y - 1];
    int hi = starts[b*NBINS + Y + 1];
    float Yf = (float)Y;
    for (int i = lo + threadIdx.x; i < hi; i += 256) {
      float4 r = recs[i];
      float wy = 1.0f - fabsf(r.y - Yf);
      if (wy <= 0.0f) continue;
      float p0 = r.x, p2 = r.z;
      float fl0 = floorf(p0), fl2 = floorf(p2);
      #pragma unroll
      for (int xo = 0; xo < 2; ++xo) {
        float px = fl0 + (float)xo;
        if (!(px > 0.0f && px < 100.0f)) continue;
        float wxy = (1.0f - fabsf(p0 - px)) * wy;
        if (wxy <= 0.0f) continue;
        int ix = (int)px;
        #pragma unroll
        for (int zo = 0; zo < 2; ++zo) {
          float pz = fl2 + (float)zo;
          if (!(pz > 0.0f && pz < 80.0f)) continue;
          float w = wxy * (1.0f - fabsf(p2 - pz));
          if (w > 0.0f) atomicAdd(&g[ix*81 + (int)pz], w);
        }
      }
    }
  }
  __syncthreads();
  if (threadIdx.x < NVR) {
    int x = threadIdx.x;
    float s_all = 0.0f, s_ag = 0.0f;
    for (int z = 0; z < NNZ; ++z) {
      float v = rintf(g[x*81 + z]);
      s_all += v;
      if (z >= ZLO && z < ZHI) s_ag += v;
    }
    float fp_map = fminf(fmaxf(s_ag, 0.0f), 1.0f);
    float fp_exp = fminf(fmaxf(s_all, 0.0f), 1.0f);
    size_t pb = (((size_t)b*NC + 0)*NVR + Y)*NVR + x;
    proj[pb] = fp_map;
    proj[pb + NVR*NVR] = fp_exp;
    proj[pb + 2*NVR*NVR] = 0.0f;
    proj[pb + 3*NVR*NVR] = 0.0f;
    out_fp[(size_t)b*NVR*NVR + Y*NVR + x] = fp_map;
  }
}

__global__ __launch_bounds__(256) void slab1_kernel(
    const float* __restrict__ obs, const float4* __restrict__ recs,
    const int* __restrict__ starts, float* __restrict__ proj)
{
  int half = blockIdx.x & 1;
  int t = blockIdx.x >> 1;
  int b = t / NVR, Y = t % NVR;
  __shared__ float g[NVR*NZB*8];
  for (int i = threadIdx.x; i < NVR*NZB*8; i += 256) g[i] = 0.0f;
  __syncthreads();
  if (Y > 0) {
    int lo = starts[b*NBINS + Y - 1];
    int hi = starts[b*NBINS + Y + 1];
    float Yf = (float)Y;
    const float* sbase = obs + ((size_t)b*NC + 4 + half*8)*NPIX;
    for (int i = lo + threadIdx.x; i < hi; i += 256) {
      float4 r = recs[i];
      float wy = 1.0f - fabsf(r.y - Yf);
      if (wy <= 0.0f) continue;
      float p2 = r.z;
      float fl2 = floorf(p2);
      float wz[2]; int iz[2]; bool any = false;
      #pragma unroll
      for (int zo = 0; zo < 2; ++zo) {
        float pz = fl2 + (float)zo;
        bool v = (pz >= (float)ZLO) && (pz < (float)ZHI);
        float w = v ? (1.0f - fabsf(p2 - pz)) : 0.0f;
        wz[zo] = w; iz[zo] = v ? ((int)pz - ZLO) : 0;
        any = any || (w > 0.0f);
      }
      if (!any) continue;
      float p0 = r.x;
      float fl0 = floorf(p0);
      int pid = __float_as_int(r.w);
      float sem[8];
      #pragma unroll
      for (int s = 0; s < 8; ++s) sem[s] = sbase[(size_t)s*NPIX + pid];
      #pragma unroll
      for (int xo = 0; xo < 2; ++xo) {
        float px = fl0 + (float)xo;
        if (!(px > 0.0f && px < 100.0f)) continue;
        float wxy = (1.0f - fabsf(p0 - px)) * wy;
        if (wxy <= 0.0f) continue;
        int ix = (int)px;
        #pragma unroll
        for (int zo = 0; zo < 2; ++zo) {
          float w = wxy * wz[zo];
          if (w > 0.0f) {
            float* gb = &g[(ix*NZB + iz[zo])*8];
            #pragma unroll
            for (int s = 0; s < 8; ++s) atomicAdd(&gb[s], w * sem[s]);
          }
        }
      }
    }
  }
  __syncthreads();
  for (int p = threadIdx.x; p < NVR*8; p += 256) {
    int x = p >> 3, s = p & 7;
    float acc = 0.0f;
    #pragma unroll
    for (int z = 0; z < NZB; ++z) acc += rintf(g[(x*NZB + z)*8 + s]);
    float val = fminf(fmaxf(acc / 5.0f, 0.0f), 1.0f);
    proj[(((size_t)b*NC + 4 + half*8 + s)*NVR + Y)*NVR + x] = val;
  }
}

// ---------------- fused rotate+translate grid_sample + max ----------------
__global__ __launch_bounds__(256) void transform_kernel(
    const float* __restrict__ maps_last, const float* __restrict__ proj,
    const float* __restrict__ params, float* __restrict__ d_out)
{
  int tid = blockIdx.x * 256 + threadIdx.x;
  int b = tid / (NM*NM);
  int rem = tid - b*(NM*NM);
  int h = rem / NM;
  int w = rem - h*NM;

  float ct = params[b*4+0];
  float st = params[b*4+1];
  float tx = params[b*4+2];
  float ty = params[b*4+3];

  const float step = 2.0f/479.0f;
  float gx = -1.0f + (float)w * step;
  float gy = -1.0f + (float)h * step;
  float X2 = ((gx + tx) + 1.0f) * 0.5f * 479.0f;
  float Y2 = ((gy + ty) + 1.0f) * 0.5f * 479.0f;
  float x0 = floorf(X2), y0 = floorf(Y2);
  float wox[2] = {(x0 + 1.0f) - X2, X2 - x0};
  float woy[2] = {(y0 + 1.0f) - Y2, Y2 - y0};

  float twt[16];
  int   toff[16];
  int nz = 0;
  #pragma unroll
  for (int oy = 0; oy < 2; ++oy) {
    #pragma unroll
    for (int ox = 0; ox < 2; ++ox) {
      int kb = (oy*2 + ox)*4;
      float cx = x0 + (float)ox;
      float cy = y0 + (float)oy;
      float wo = wox[ox]*woy[oy];
      bool ov = (cx >= 0.0f) && (cx <= 479.0f) && (cy >= 0.0f) && (cy <= 479.0f);
      if (ov) {
        float gxr = -1.0f + cx * step;
        float gyr = -1.0f + cy * step;
        float xr = gxr*ct - gyr*st;
        float yr = gxr*st + gyr*ct;
        float XS = (xr + 1.0f)*0.5f*479.0f;
        float YS = (yr + 1.0f)*0.5f*479.0f;
        float ix0 = floorf(XS), iy0 = floorf(YS);
        float wix[2] = {(ix0+1.0f)-XS, XS-ix0};
        float wiy[2] = {(iy0+1.0f)-YS, YS-iy0};
        #pragma unroll
        for (int qy = 0; qy < 2; ++qy) {
          #pragma unroll
          for (int qx = 0; qx < 2; ++qx) {
            int k = kb + qy*2 + qx;
            float ux = ix0 + (float)qx;
            float vy = iy0 + (float)qy;
            float wv = 0.0f; int off = 0;
            if (ux >= 0.0f && ux <= 479.0f && vy >= 0.0f && vy <= 479.0f) {
              int U = (int)ux, V = (int)vy;
              if (U >= 190 && U < 290 && V >= 240 && V < 340) {
                off = (V - 240)*NVR + (U - 190);
                wv = wo * (wix[qx]*wiy[qy]);
              }
            }
            twt[k] = wv; toff[k] = off;
            nz += (wv != 0.0f) ? 1 : 0;
          }
        }
      } else {
        #pragma unroll
        for (int k = 0; k < 4; ++k) { twt[kb+k] = 0.0f; toff[kb+k] = 0; }
      }
    }
  }

  const float* pbase = proj + (size_t)b*NC*NVR*NVR;
  size_t base_idx = (size_t)b*NC*NM*NM + (size_t)h*NM + w;
  if (nz > 0) {
    #pragma unroll 1
    for (int c = 0; c < NC; ++c) {
      size_t idx = base_idx + (size_t)c*NM*NM;
      float ml = maps_last[idx];
      float val = 0.0f;
      if (c != 2 && c != 3) {
        const float* pc = pbase + (size_t)c*NVR*NVR;
        #pragma unroll
        for (int k = 0; k < 16; ++k) val += twt[k]*pc[toff[k]];
      }
      d_out[40000 + idx] = fmaxf(ml, val);
    }
  } else {
    #pragma unroll 1
    for (int c = 0; c < NC; ++c) {
      size_t idx = base_idx + (size_t)c*NM*NM;
      d_out[40000 + idx] = fmaxf(maps_last[idx], 0.0f);
    }
  }
}

extern "C" void kernel_launch(void* const* d_in, const int* in_sizes, int n_in,
                              void* d_out, int out_size, void* d_ws, size_t ws_size,
                              hipStream_t stream)
{
  const float* obs        = (const float*)d_in[0];
  const float* pose_obs   = (const float*)d_in[1];
  const float* maps_last  = (const float*)d_in[2];
  const float* poses_last = (const float*)d_in[3];
  float* out = (float*)d_out;

  char* ws = (char*)d_ws;
  int*    hist    = (int*)(ws + WS_HIST);
  int*    hist2   = (int*)(ws + WS_HIST2);
  int*    starts  = (int*)(ws + WS_STARTS);
  int*    starts2 = (int*)(ws + WS_STARTS2);
  int*    cursors = (int*)(ws + WS_CURS);
  int*    cursors2= (int*)(ws + WS_CURS2);
  float*  params  = (float*)(ws + WS_PARAMS);
  float4* recs    = (float4*)(ws + WS_RECS);
  float*  proj    = (float*)(ws + WS_PROJ);
  float4* sgeom   = (float4*)(ws + WS_SGEOM);

  const bool fast = ws_size >= (size_t)WS_FAST_END;

  hipMemsetAsync(ws, 0, WS_PARAMS, stream);    // hist/hist2/starts/cursors

  const float foc = (float)(((double)NW) / 2.0 / tan(79.0 * 0.5 * M_PI / 180.0));

  pose_kernel<<<1, 64, 0, stream>>>(pose_obs, poses_last, out + 40000 + 18432000, params);
  hist_kernel<<<NB*300, 256, 0, stream>>>(obs, hist, hist2, foc);
  scan_kernel<<<1, 512, 0, stream>>>(hist, hist2, starts, cursors, starts2, cursors2);
  scatter_kernel<<<NB*300, 256, 0, stream>>>(obs, cursors, cursors2, recs, sgeom,
                                             foc, fast ? 1 : 0);
  if (fast) {
    slabs_kernel<<<SLAB_GRID, 256, 0, stream>>>(obs, recs, sgeom, starts, starts2,
                                                proj, out);
  } else {
    slab0_kernel<<<NB*NVR, 256, 0, stream>>>(recs, starts, proj, out);
    slab1_kernel<<<NB*NVR*2, 256, 0, stream>>>(obs, recs, starts, proj);
  }
  transform_kernel<<<(NB*NM*NM)/256, 256, 0, stream>>>(maps_last, proj, params, out);
}

// Round 4
// 613.878 us; speedup vs baseline: 1.0194x; 1.0194x over previous
//
#include <hip/hip_runtime.h>
#include <math.h>

#define NB 4
#define NC 20
#define NH 480
#define NW 640
#define NPIX (NH*NW)      // 307200
#define NM 480
#define NVR 100
#define NNZ 80
#define ZLO 13
#define ZHI 25
#define NZB 12
#define NSEM_ 16
#define NBINS 101         // y0 bucket 0..100 (100 = dead)
#define SREC_CAP 655360   // band-record capacity (expected ~310K)

// dense window (Y<=YDEN -> d<125): p0 in [29.4,70.6], p2 in [10.2,41.0]
#define YDEN 24
#define DX0 28
#define DXW 44            // x cells [28,72)
#define DZ0 9
#define DZW 34            // z cells [9,43)
#define R0STR 1497        // slab0 replica stride (44*34=1496, +1 for bank spread)
#define R0N 6             // 6*1497 = 8982 <= 9600
#define SCHSTR 529        // sem channel stride (44*12=528, +1 for bank spread)
#define SREPSTR 4232      // sem replica stride (8*529)
#define SREPN 2           // 2*4232 = 8464 <= 9600

// workspace offsets
#define WS_HIST     0
#define WS_HIST2    2048
#define WS_STARTS   4096
#define WS_STARTS2  6144
#define WS_CURS     8192
#define WS_CURS2    10240
#define WS_PARAMS   12288
#define WS_RECS     16384
#define WS_PROJ     (WS_RECS + 19660800)
#define WS_SGEOM    (WS_PROJ + 3200000)
#define WS_FAST_END (WS_SGEOM + (size_t)SREC_CAP*16) // 33,362,944

// exact replication of the reference f32 op chains
__device__ __forceinline__ float p1_chain(float d) {
  float xy1 = d / 5.0f;
  xy1 = (xy1 - 50.0f) / 100.0f * 2.0f;
  return xy1 * 50.0f + 50.0f;
}
__device__ __forceinline__ void p02_chain(float d, int row, int col, float foc,
                                          float& p0, float& p2) {
  float X = ((float)col - 319.5f) * d / foc;
  float Z = ((float)(479 - row) - 239.5f) * d / foc;
  float xy0 = (X + 250.0f) / 5.0f;
  xy0 = (xy0 - 50.0f) / 100.0f * 2.0f;
  float zz = (Z + 88.0f) / 5.0f;
  zz = (zz - 32.0f) / 80.0f * 2.0f;
  p0 = xy0 * 50.0f + 50.0f;
  p2 = zz * 40.0f + 40.0f;
}
__device__ __forceinline__ bool band_ok(float p0, float p2) {
  return (p0 > 0.0f) && (p0 < 100.0f) &&
         (p2 > (float)(ZLO - 1)) && (p2 < (float)ZHI);
}
// 4-way select without LDS/scratch (cb runtime 0..3)
__device__ __forceinline__ float mux4f(int cb, float v0, float v1, float v2, float v3) {
  float a = (cb & 1) ? v1 : v0;
  float b = (cb & 1) ? v3 : v2;
  return (cb & 2) ? b : a;
}
__device__ __forceinline__ int mux4i(int cb, int v0, int v1, int v2, int v3) {
  int a = (cb & 1) ? v1 : v0;
  int b = (cb & 1) ? v3 : v2;
  return (cb & 2) ? b : a;
}

// ---------------- pose + affine params ----------------
__global__ __launch_bounds__(64) void pose_kernel(
    const float* __restrict__ pose_obs, const float* __restrict__ poses_last,
    float* __restrict__ out_poses, float* __restrict__ params)
{
  int b = threadIdx.x;
  if (b >= NB) return;
  const float R2D = 57.29577951308232f;
  float plx = poses_last[b*3+0], ply = poses_last[b*3+1], plo = poses_last[b*3+2];
  float dx = pose_obs[b*3+0], dy = pose_obs[b*3+1], dth = pose_obs[b*3+2];
  float r = plo / R2D;
  float sr = sinf(r), cr = cosf(r);
  float yy = ply + dx*sr + dy*cr;
  float xx = plx + dx*cr - dy*sr;
  float oo = plo + dth*R2D;
  oo = fmodf(oo - 180.0f, 360.0f) + 180.0f;
  oo = fmodf(oo + 180.0f, 360.0f) - 180.0f;
  out_poses[b*3+0] = xx;
  out_poses[b*3+1] = yy;
  out_poses[b*3+2] = oo;
  float tx = -((xx*100.0f/5.0f) - 240.0f) / 240.0f;
  float ty = -((yy*100.0f/5.0f) - 240.0f) / 240.0f;
  float th = ((90.0f - oo) * 3.14159274101257324f) / 180.0f;
  params[b*4+0] = cosf(th);
  params[b*4+1] = sinf(th);
  params[b*4+2] = tx;
  params[b*4+3] = ty;
}

// ---------------- histogram by y-bucket (all + band-filtered) ----------------
__global__ __launch_bounds__(256) void hist_kernel(
    const float* __restrict__ obs, int* __restrict__ hist, int* __restrict__ hist2,
    float foc)
{
  int b = blockIdx.x / 300, blk = blockIdx.x % 300;
  __shared__ int lh[NBINS], lh2[NBINS];
  for (int i = threadIdx.x; i < NBINS; i += 256) { lh[i] = 0; lh2[i] = 0; }
  __syncthreads();
  int pix0 = (blk*256 + threadIdx.x)*4;
  int row = pix0 / NW;
  int c0 = pix0 - row*NW;
  const float4* dp = (const float4*)(obs + ((size_t)b*NC + 3)*NPIX);
  float4 dv = dp[blk*256 + threadIdx.x];
  float dvv[4] = {dv.x, dv.y, dv.z, dv.w};
  #pragma unroll
  for (int k = 0; k < 4; ++k) {
    float p1 = p1_chain(dvv[k]);
    int y0 = (int)floorf(p1);
    y0 = min(max(y0, 0), 100);
    atomicAdd(&lh[y0], 1);
    float p0, p2;
    p02_chain(dvv[k], row, c0 + k, foc, p0, p2);
    if (band_ok(p0, p2)) atomicAdd(&lh2[y0], 1);
  }
  __syncthreads();
  for (int i = threadIdx.x; i < NBINS; i += 256) {
    if (lh[i])  atomicAdd(&hist[b*NBINS + i],  lh[i]);
    if (lh2[i]) atomicAdd(&hist2[b*NBINS + i], lh2[i]);
  }
}

// ---------------- exclusive scan of both bin arrays ----------------
__global__ __launch_bounds__(512) void scan_kernel(
    const int* __restrict__ hist, const int* __restrict__ hist2,
    int* __restrict__ starts, int* __restrict__ cursors,
    int* __restrict__ starts2, int* __restrict__ cursors2)
{
  __shared__ int lh[NB*NBINS], lh2[NB*NBINS];
  __shared__ int ls[NB*NBINS + 1], ls2[NB*NBINS + 1];
  for (int i = threadIdx.x; i < NB*NBINS; i += 512) { lh[i] = hist[i]; lh2[i] = hist2[i]; }
  __syncthreads();
  if (threadIdx.x == 0) {
    int s = 0;
    for (int i = 0; i < NB*NBINS; ++i) { ls[i] = s; s += lh[i]; }
    ls[NB*NBINS] = s;
  }
  if (threadIdx.x == 1) {
    int s = 0;
    for (int i = 0; i < NB*NBINS; ++i) { ls2[i] = s; s += lh2[i]; }
    ls2[NB*NBINS] = s;
  }
  __syncthreads();
  for (int i = threadIdx.x; i < NB*NBINS + 1; i += 512) {
    starts[i] = ls[i];
    starts2[i] = ls2[i];
    if (i < NB*NBINS) { cursors[i] = ls[i]; cursors2[i] = ls2[i]; }
  }
}

// ---------------- scatter pixel records into buckets ----------------
__global__ __launch_bounds__(256) void scatter_kernel(
    const float* __restrict__ obs, int* __restrict__ cursors, int* __restrict__ cursors2,
    float4* __restrict__ recs, float4* __restrict__ sgeom,
    float foc, int do_band)
{
  int b = blockIdx.x / 300, blk = blockIdx.x % 300;
  __shared__ int lh[NBINS], lbase[NBINS], loff[NBINS];
  __shared__ int lh2[NBINS], lbase2[NBINS], loff2[NBINS];
  for (int i = threadIdx.x; i < NBINS; i += 256) {
    lh[i] = 0; loff[i] = 0; lh2[i] = 0; loff2[i] = 0;
  }
  __syncthreads();
  int pix0 = (blk*256 + threadIdx.x)*4;
  int row = pix0 / NW;
  int c0 = pix0 - row*NW;   // 4-pixel group never crosses a row (640 % 4 == 0)
  const float4* dp = (const float4*)(obs + ((size_t)b*NC + 3)*NPIX);
  float4 dv = dp[blk*256 + threadIdx.x];
  float dvv[4] = {dv.x, dv.y, dv.z, dv.w};
  float rp0[4], rp1[4], rp2[4]; int rbin[4]; bool rb[4];
  #pragma unroll
  for (int k = 0; k < 4; ++k) {
    float p1 = p1_chain(dvv[k]);
    float p0, p2;
    p02_chain(dvv[k], row, c0 + k, foc, p0, p2);
    rp0[k] = p0; rp1[k] = p1; rp2[k] = p2;
    int y0 = (int)floorf(p1); y0 = min(max(y0, 0), 100);
    rbin[k] = y0;
    atomicAdd(&lh[y0], 1);
    rb[k] = do_band && band_ok(p0, p2);
    if (rb[k]) atomicAdd(&lh2[y0], 1);
  }
  __syncthreads();
  for (int i = threadIdx.x; i < NBINS; i += 256) {
    if (lh[i]  > 0) lbase[i]  = atomicAdd(&cursors[b*NBINS + i],  lh[i]);
    if (lh2[i] > 0) lbase2[i] = atomicAdd(&cursors2[b*NBINS + i], lh2[i]);
  }
  __syncthreads();
  #pragma unroll
  for (int k = 0; k < 4; ++k) {
    int idx = atomicAdd(&loff[rbin[k]], 1);
    recs[lbase[rbin[k]] + idx] =
        make_float4(rp0[k], rp1[k], rp2[k], __int_as_float(pix0 + k));
    if (rb[k]) {
      int j = lbase2[rbin[k]] + atomicAdd(&loff2[rbin[k]], 1);
      if (j < SREC_CAP)
        sgeom[j] = make_float4(rp0[k], rp1[k], rp2[k], __int_as_float(pix0 + k));
    }
  }
}

// ---------------- fused slab kernel, 1200 blocks, one tile each ----------------
// t < 400: ch0 slab (b=t/100, Y=t%100)
// t >= 400: sem slab (tt=t-400; half=tt&1; b,Y from tt>>1)
// Anti-collision:
//  - per-lane rotation of atomic issue order (corners by (tid>>3)&3, channels by tid&7)
//  - Y<=24 (d<125, correct foc=388.2): windowed replicated accumulators
//    slab0: z-major [z:34][x:44] x6 replicas; sem: [ch:8][x:44][z:12] x2 replicas
__global__ __launch_bounds__(256) void slabs_kernel(
    const float* __restrict__ obs,
    const float4* __restrict__ recs, const float4* __restrict__ sgeom,
    const int* __restrict__ starts, const int* __restrict__ starts2,
    float* __restrict__ proj, float* __restrict__ out_fp)
{
  __shared__ float g[9600];
  const int t = blockIdx.x;
  for (int i = threadIdx.x; i < 9600; i += 256) g[i] = 0.0f;
  __syncthreads();

  if (t < 400) {
    // ---------------- ch0 slab ----------------
    const int b = t / NVR, Y = t % NVR;
    const bool dense = (Y >= 1 && Y <= YDEN);
    if (Y > 0) {
      const int lo = starts[b*NBINS + Y - 1];
      const int hi = starts[b*NBINS + Y + 1];
      const float Yf = (float)Y;
      const int cr = (threadIdx.x >> 3) & 3;
      const int rbase = dense ? R0STR * (threadIdx.x % R0N) : 0;
      for (int i = lo + threadIdx.x; i < hi; i += 256) {
        float4 r = recs[i];
        float wy = 1.0f - fabsf(r.y - Yf);
        if (wy <= 0.0f) continue;
        float p0 = r.x, p2 = r.z;
        float fl0 = floorf(p0), fl2 = floorf(p2);
        float px0 = fl0, px1 = fl0 + 1.0f;
        float pz0 = fl2, pz1 = fl2 + 1.0f;
        float wx0 = (px0 > 0.0f && px0 < 100.0f) ? (1.0f - fabsf(p0 - px0)) * wy : 0.0f;
        float wx1 = (px1 > 0.0f && px1 < 100.0f) ? (1.0f - fabsf(p0 - px1)) * wy : 0.0f;
        float wz0 = (pz0 > 0.0f && pz0 < 80.0f) ? (1.0f - fabsf(p2 - pz0)) : 0.0f;
        float wz1 = (pz1 > 0.0f && pz1 < 80.0f) ? (1.0f - fabsf(p2 - pz1)) : 0.0f;
        int ix0 = (int)px0, ix1 = ix0 + 1, iz0 = (int)pz0, iz1 = iz0 + 1;
        int a0, a1, a2, a3;
        if (dense) {
          // z-major within window: addr = rbase + (z-DZ0)*DXW + (x-DX0)
          int x0l = ix0 - DX0, x1l = x0l + 1, z0l = iz0 - DZ0, z1l = z0l + 1;
          a0 = rbase + z0l*DXW + x0l; a1 = rbase + z0l*DXW + x1l;
          a2 = rbase + z1l*DXW + x0l; a3 = rbase + z1l*DXW + x1l;
        } else {
          a0 = ix0*81 + iz0; a1 = ix1*81 + iz0;
          a2 = ix0*81 + iz1; a3 = ix1*81 + iz1;
        }
        float w0 = wx0*wz0, w1 = wx1*wz0, w2 = wx0*wz1, w3 = wx1*wz1;
        #pragma unroll
        for (int kc = 0; kc < 4; ++kc) {
          int cb = (kc + cr) & 3;
          float w = mux4f(cb, w0, w1, w2, w3);
          int   a = mux4i(cb, a0, a1, a2, a3);
          if (w > 0.0f) atomicAdd(&g[a], w);
        }
      }
    }
    __syncthreads();
    if (threadIdx.x < NVR) {
      int x = threadIdx.x;
      float s_all = 0.0f, s_ag = 0.0f;
      if (dense) {
        if (x >= DX0 && x < DX0 + DXW) {
          int xl = x - DX0;
          for (int zl = 0; zl < DZW; ++zl) {
            float s = 0.0f;
            #pragma unroll
            for (int rp = 0; rp < R0N; ++rp) s += g[rp*R0STR + zl*DXW + xl];
            float v = rintf(s);
            int z = zl + DZ0;
            s_all += v;
            if (z >= ZLO && z < ZHI) s_ag += v;
          }
        }
      } else {
        for (int z = 0; z < NNZ; ++z) {
          float v = rintf(g[x*81 + z]);
          s_all += v;
          if (z >= ZLO && z < ZHI) s_ag += v;
        }
      }
      float fp_map = fminf(fmaxf(s_ag, 0.0f), 1.0f);
      float fp_exp = fminf(fmaxf(s_all, 0.0f), 1.0f);
      size_t pb = (((size_t)b*NC + 0)*NVR + Y)*NVR + x;
      proj[pb] = fp_map;
      proj[pb + NVR*NVR] = fp_exp;
      proj[pb + 2*NVR*NVR] = 0.0f;
      proj[pb + 3*NVR*NVR] = 0.0f;
      out_fp[(size_t)b*NVR*NVR + Y*NVR + x] = fp_map;
    }
  } else {
    // ---------------- sem slab (8 channels) ----------------
    const int tt = t - 400;
    const int half = tt & 1;
    const int by = tt >> 1;
    const int b = by / NVR, Y = by % NVR;
    const bool dense = (Y >= 1 && Y <= YDEN);
    if (Y > 0) {
      const int lo = starts2[b*NBINS + Y - 1];
      const int hi = starts2[b*NBINS + Y + 1];
      const float Yf = (float)Y;
      const float* sbase = obs + ((size_t)b*NC + 4 + half*8)*NPIX;
      const int r8 = threadIdx.x & 7;
      const int cr = (threadIdx.x >> 3) & 3;
      const int rbase = dense ? SREPSTR * ((threadIdx.x >> 5) & (SREPN - 1)) : 0;
      const int stride = dense ? SCHSTR : 1200;
      int soff[8], choff[8];
      #pragma unroll
      for (int k = 0; k < 8; ++k) {
        int ch = (k + r8) & 7;
        soff[k] = ch * stride;
        choff[k] = ch * NPIX;
      }
      for (int i = lo + threadIdx.x; i < hi; i += 256) {
        float4 r = sgeom[i];
        float wy = 1.0f - fabsf(r.y - Yf);
        if (wy <= 0.0f) continue;
        float p2 = r.z;
        float fl2 = floorf(p2);
        float pz0 = fl2, pz1 = fl2 + 1.0f;
        bool v0 = (pz0 >= (float)ZLO) && (pz0 < (float)ZHI);
        bool v1 = (pz1 >= (float)ZLO) && (pz1 < (float)ZHI);
        float wz0 = v0 ? (1.0f - fabsf(p2 - pz0)) : 0.0f;
        float wz1 = v1 ? (1.0f - fabsf(p2 - pz1)) : 0.0f;
        int iz0 = v0 ? ((int)pz0 - ZLO) : 0;
        int iz1 = v1 ? ((int)pz1 - ZLO) : 0;
        if (wz0 <= 0.0f && wz1 <= 0.0f) continue;
        float p0 = r.x;
        float fl0 = floorf(p0);
        float px0 = fl0, px1 = fl0 + 1.0f;
        float wx0 = (px0 > 0.0f && px0 < 100.0f) ? (1.0f - fabsf(p0 - px0)) * wy : 0.0f;
        float wx1 = (px1 > 0.0f && px1 < 100.0f) ? (1.0f - fabsf(p0 - px1)) * wy : 0.0f;
        int ix0 = (int)px0, ix1 = ix0 + 1;
        int pid = __float_as_int(r.w);
        float sem[8];
        #pragma unroll
        for (int k = 0; k < 8; ++k) sem[k] = sbase[(size_t)choff[k] + pid];
        int c00, c10, c01, c11;
        if (dense) {
          int x0l = ix0 - DX0, x1l = x0l + 1;
          c00 = x0l*NZB + iz0; c10 = x1l*NZB + iz0;
          c01 = x0l*NZB + iz1; c11 = x1l*NZB + iz1;
        } else {
          c00 = ix0*NZB + iz0; c10 = ix1*NZB + iz0;
          c01 = ix0*NZB + iz1; c11 = ix1*NZB + iz1;
        }
        float w00 = wx0*wz0, w10 = wx1*wz0, w01 = wx0*wz1, w11 = wx1*wz1;
        #pragma unroll
        for (int kc = 0; kc < 4; ++kc) {
          int cb = (kc + cr) & 3;
          float w  = mux4f(cb, w00, w10, w01, w11);
          int cell = mux4i(cb, c00, c10, c01, c11);
          if (w > 0.0f) {
            int ga = rbase + cell;
            #pragma unroll
            for (int k = 0; k < 8; ++k)
              atomicAdd(&g[ga + soff[k]], w * sem[k]);
          }
        }
      }
    }
    __syncthreads();
    for (int p = threadIdx.x; p < NVR*8; p += 256) {
      int x = p >> 3, s = p & 7;
      float acc = 0.0f;
      if (dense) {
        if (x >= DX0 && x < DX0 + DXW) {
          int xl = x - DX0;
          #pragma unroll
          for (int z = 0; z < NZB; ++z) {
            int c = s*SCHSTR + xl*NZB + z;
            float sum = g[c] + g[SREPSTR + c];
            acc += rintf(sum);
          }
        }
      } else {
        #pragma unroll
        for (int z = 0; z < NZB; ++z) acc += rintf(g[s*1200 + x*NZB + z]);
      }
      float val = fminf(fmaxf(acc / 5.0f, 0.0f), 1.0f);
      proj[(((size_t)b*NC + 4 + half*8 + s)*NVR + Y)*NVR + x] = val;
    }
  }
}

// ---------------- fallback (ws too small) slab kernels ----------------
__global__ __launch_bounds__(256) void slab0_kernel(
    const float4* __restrict__ recs, const int* __restrict__ starts,
    float* __restrict__ proj, float* __restrict__ out_fp)
{
  int b = blockIdx.x / NVR, Y = blockIdx.x % NVR;
  __shared__ float g[NVR*81];
  for (int i = threadIdx.x; i < NVR*81; i += 256) g[i] = 0.0f;
  __syncthreads();
  if (Y > 0) {
    int lo = starts[b*NBINS + Y - 1];
    int hi = starts[b*NBINS + Y + 1];
    float Yf = (float)Y;
    for (int i = lo + threadIdx.x; i < hi; i += 256) {
      float4 r = recs[i];
      float wy = 1.0f - fabsf(r.y - Yf);
      if (wy <= 0.0f) continue;
      float p0 = r.x, p2 = r.z;
      float fl0 = floorf(p0), fl2 = floorf(p2);
      #pragma unroll
      for (int xo = 0; xo < 2; ++xo) {
        float px = fl0 + (float)xo;
        if (!(px > 0.0f && px < 100.0f)) continue;
        float wxy = (1.0f - fabsf(p0 - px)) * wy;
        if (wxy <= 0.0f) continue;
        int ix = (int)px;
        #pragma unroll
        for (int zo = 0; zo < 2; ++zo) {
          float pz = fl2 + (float)zo;
          if (!(pz > 0.0f && pz < 80.0f)) continue;
          float w = wxy * (1.0f - fabsf(p2 - pz));
          if (w > 0.0f) atomicAdd(&g[ix*81 + (int)pz], w);
        }
      }
    }
  }
  __syncthreads();
  if (threadIdx.x < NVR) {
    int x = threadIdx.x;
    float s_all = 0.0f, s_ag = 0.0f;
    for (int z = 0; z < NNZ; ++z) {
      float v = rintf(g[x*81 + z]);
      s_all += v;
      if (z >= ZLO && z < ZHI) s_ag += v;
    }
    float fp_map = fminf(fmaxf(s_ag, 0.0f), 1.0f);
    float fp_exp = fminf(fmaxf(s_all, 0.0f), 1.0f);
    size_t pb = (((size_t)b*NC + 0)*NVR + Y)*NVR + x;
    proj[pb] = fp_map;
    proj[pb + NVR*NVR] = fp_exp;
    proj[pb + 2*NVR*NVR] = 0.0f;
    proj[pb + 3*NVR*NVR] = 0.0f;
    out_fp[(size_t)b*NVR*NVR + Y*NVR + x] = fp_map;
  }
}

__global__ __launch_bounds__(256) void slab1_kernel(
    const float* __restrict__ obs, const float4* __restrict__ recs,
    const int* __restrict__ starts, float* __restrict__ proj)
{
  int half = blockIdx.x & 1;
  int t = blockIdx.x >> 1;
  int b = t / NVR, Y = t % NVR;
  __shared__ float g[NVR*NZB*8];
  for (int i = threadIdx.x; i < NVR*NZB*8; i += 256) g[i] = 0.0f;
  __syncthreads();
  if (Y > 0) {
    int lo = starts[b*NBINS + Y - 1];
    int hi = starts[b*NBINS + Y + 1];
    float Yf = (float)Y;
    const float* sbase = obs + ((size_t)b*NC + 4 + half*8)*NPIX;
    for (int i = lo + threadIdx.x; i < hi; i += 256) {
      float4 r = recs[i];
      float wy = 1.0f - fabsf(r.y - Yf);
      if (wy <= 0.0f) continue;
      float p2 = r.z;
      float fl2 = floorf(p2);
      float wz[2]; int iz[2]; bool any = false;
      #pragma unroll
      for (int zo = 0; zo < 2; ++zo) {
        float pz = fl2 + (float)zo;
        bool v = (pz >= (float)ZLO) && (pz < (float)ZHI);
        float w = v ? (1.0f - fabsf(p2 - pz)) : 0.0f;
        wz[zo] = w; iz[zo] = v ? ((int)pz - ZLO) : 0;
        any = any || (w > 0.0f);
      }
      if (!any) continue;
      float p0 = r.x;
      float fl0 = floorf(p0);
      int pid = __float_as_int(r.w);
      float sem[8];
      #pragma unroll
      for (int s = 0; s < 8; ++s) sem[s] = sbase[(size_t)s*NPIX + pid];
      #pragma unroll
      for (int xo = 0; xo < 2; ++xo) {
        float px = fl0 + (float)xo;
        if (!(px > 0.0f && px < 100.0f)) continue;
        float wxy = (1.0f - fabsf(p0 - px)) * wy;
        if (wxy <= 0.0f) continue;
        int ix = (int)px;
        #pragma unroll
        for (int zo = 0; zo < 2; ++zo) {
          float w = wxy * wz[zo];
          if (w > 0.0f) {
            float* gb = &g[(ix*NZB + iz[zo])*8];
            #pragma unroll
            for (int s = 0; s < 8; ++s) atomicAdd(&gb[s], w * sem[s]);
          }
        }
      }
    }
  }
  __syncthreads();
  for (int p = threadIdx.x; p < NVR*8; p += 256) {
    int x = p >> 3, s = p & 7;
    float acc = 0.0f;
    #pragma unroll
    for (int z = 0; z < NZB; ++z) acc += rintf(g[(x*NZB + z)*8 + s]);
    float val = fminf(fmaxf(acc / 5.0f, 0.0f), 1.0f);
    proj[(((size_t)b*NC + 4 + half*8 + s)*NVR + Y)*NVR + x] = val;
  }
}

// ---------------- fused rotate+translate grid_sample + max ----------------
__global__ __launch_bounds__(256) void transform_kernel(
    const float* __restrict__ maps_last, const float* __restrict__ proj,
    const float* __restrict__ params, float* __restrict__ d_out)
{
  int tid = blockIdx.x * 256 + threadIdx.x;
  int b = tid / (NM*NM);
  int rem = tid - b*(NM*NM);
  int h = rem / NM;
  int w = rem - h*NM;

  float ct = params[b*4+0];
  float st = params[b*4+1];
  float tx = params[b*4+2];
  float ty = params[b*4+3];

  const float step = 2.0f/479.0f;
  float gx = -1.0f + (float)w * step;
  float gy = -1.0f + (float)h * step;
  float X2 = ((gx + tx) + 1.0f) * 0.5f * 479.0f;
  float Y2 = ((gy + ty) + 1.0f) * 0.5f * 479.0f;
  float x0 = floorf(X2), y0 = floorf(Y2);
  float wox[2] = {(x0 + 1.0f) - X2, X2 - x0};
  float woy[2] = {(y0 + 1.0f) - Y2, Y2 - y0};

  float twt[16];
  int   toff[16];
  int nz = 0;
  #pragma unroll
  for (int oy = 0; oy < 2; ++oy) {
    #pragma unroll
    for (int ox = 0; ox < 2; ++ox) {
      int kb = (oy*2 + ox)*4;
      float cx = x0 + (float)ox;
      float cy = y0 + (float)oy;
      float wo = wox[ox]*woy[oy];
      bool ov = (cx >= 0.0f) && (cx <= 479.0f) && (cy >= 0.0f) && (cy <= 479.0f);
      if (ov) {
        float gxr = -1.0f + cx * step;
        float gyr = -1.0f + cy * step;
        float xr = gxr*ct - gyr*st;
        float yr = gxr*st + gyr*ct;
        float XS = (xr + 1.0f)*0.5f*479.0f;
        float YS = (yr + 1.0f)*0.5f*479.0f;
        float ix0 = floorf(XS), iy0 = floorf(YS);
        float wix[2] = {(ix0+1.0f)-XS, XS-ix0};
        float wiy[2] = {(iy0+1.0f)-YS, YS-iy0};
        #pragma unroll
        for (int qy = 0; qy < 2; ++qy) {
          #pragma unroll
          for (int qx = 0; qx < 2; ++qx) {
            int k = kb + qy*2 + qx;
            float ux = ix0 + (float)qx;
            float vy = iy0 + (float)qy;
            float wv = 0.0f; int off = 0;
            if (ux >= 0.0f && ux <= 479.0f && vy >= 0.0f && vy <= 479.0f) {
              int U = (int)ux, V = (int)vy;
              if (U >= 190 && U < 290 && V >= 240 && V < 340) {
                off = (V - 240)*NVR + (U - 190);
                wv = wo * (wix[qx]*wiy[qy]);
              }
            }
            twt[k] = wv; toff[k] = off;
            nz += (wv != 0.0f) ? 1 : 0;
          }
        }
      } else {
        #pragma unroll
        for (int k = 0; k < 4; ++k) { twt[kb+k] = 0.0f; toff[kb+k] = 0; }
      }
    }
  }

  const float* pbase = proj + (size_t)b*NC*NVR*NVR;
  size_t base_idx = (size_t)b*NC*NM*NM + (size_t)h*NM + w;
  if (nz > 0) {
    #pragma unroll 1
    for (int c = 0; c < NC; ++c) {
      size_t idx = base_idx + (size_t)c*NM*NM;
      float ml = maps_last[idx];
      float val = 0.0f;
      if (c != 2 && c != 3) {
        const float* pc = pbase + (size_t)c*NVR*NVR;
        #pragma unroll
        for (int k = 0; k < 16; ++k) val += twt[k]*pc[toff[k]];
      }
      d_out[40000 + idx] = fmaxf(ml, val);
    }
  } else {
    #pragma unroll 1
    for (int c = 0; c < NC; ++c) {
      size_t idx = base_idx + (size_t)c*NM*NM;
      d_out[40000 + idx] = fmaxf(maps_last[idx], 0.0f);
    }
  }
}

extern "C" void kernel_launch(void* const* d_in, const int* in_sizes, int n_in,
                              void* d_out, int out_size, void* d_ws, size_t ws_size,
                              hipStream_t stream)
{
  const float* obs        = (const float*)d_in[0];
  const float* pose_obs   = (const float*)d_in[1];
  const float* maps_last  = (const float*)d_in[2];
  const float* poses_last = (const float*)d_in[3];
  float* out = (float*)d_out;

  char* ws = (char*)d_ws;
  int*    hist    = (int*)(ws + WS_HIST);
  int*    hist2   = (int*)(ws + WS_HIST2);
  int*    starts  = (int*)(ws + WS_STARTS);
  int*    starts2 = (int*)(ws + WS_STARTS2);
  int*    cursors = (int*)(ws + WS_CURS);
  int*    cursors2= (int*)(ws + WS_CURS2);
  float*  params  = (float*)(ws + WS_PARAMS);
  float4* recs    = (float4*)(ws + WS_RECS);
  float*  proj    = (float*)(ws + WS_PROJ);
  float4* sgeom   = (float4*)(ws + WS_SGEOM);

  const bool fast = ws_size >= (size_t)WS_FAST_END;

  hipMemsetAsync(ws, 0, WS_PARAMS, stream);    // hist/hist2/starts/cursors

  const float foc = (float)(((double)NW) / 2.0 / tan(79.0 * 0.5 * M_PI / 180.0));

  pose_kernel<<<1, 64, 0, stream>>>(pose_obs, poses_last, out + 40000 + 18432000, params);
  hist_kernel<<<NB*300, 256, 0, stream>>>(obs, hist, hist2, foc);
  scan_kernel<<<1, 512, 0, stream>>>(hist, hist2, starts, cursors, starts2, cursors2);
  scatter_kernel<<<NB*300, 256, 0, stream>>>(obs, cursors, cursors2, recs, sgeom,
                                             foc, fast ? 1 : 0);
  if (fast) {
    slabs_kernel<<<1200, 256, 0, stream>>>(obs, recs, sgeom, starts, starts2,
                                           proj, out);
  } else {
    slab0_kernel<<<NB*NVR, 256, 0, stream>>>(recs, starts, proj, out);
    slab1_kernel<<<NB*NVR*2, 256, 0, stream>>>(obs, recs, starts, proj);
  }
  transform_kernel<<<(NB*NM*NM)/256, 256, 0, stream>>>(maps_last, proj, params, out);
}